// Round 11
// baseline (462.317 us; speedup 1.0000x reference)
//
#include <hip/hip_runtime.h>
#include <math.h>

#define N_NODES 100000
#define N_EDGES 3200000
#define D_IN    256
#define D_OUT   128
#define ALPHA   0.2f

// counting-sort chunking: per-block LDS-privatized histogram
#define NB_HIST 125                    // chunks == hist blocks
#define CHUNK   (N_EDGES / NB_HIST)    // 25600 edges per chunk (25600 % 1024 == 0)
#define HWORDS  (N_NODES / 4)          // 25000 packed u8x4 bins = 100 KB LDS
#define NGRP    5                      // chunk groups for parallel scan
#define GLEN    (NB_HIST / NGRP)       // 25 chunks per group
// bucket sort of final positions: records clustered so scatter writes are dense
#define NBUK    256                    // position buckets
#define BW      (N_EDGES / NBUK)       // 12500 positions per bucket (50 KB window)
#define P1TILE  2560                   // edges per bucket block (CHUNK/10 -> chunk uniform)
#define P1PT    (P1TILE / 256)         // 10 edges per thread (register stash)

typedef short bf8_t  __attribute__((ext_vector_type(8)));   // 8 bf16 (MFMA A/B frag)
typedef float f4_t   __attribute__((ext_vector_type(4)));   // 4 f32  (MFMA C/D frag)

// round-to-nearest-even f32 -> bf16
__device__ __forceinline__ unsigned int f2bf(float x) {
    unsigned int u = __float_as_uint(x);
    return (u + 0x7fffu + ((u >> 16) & 1u)) >> 16;
}
__device__ __forceinline__ unsigned int packbf(float lo, float hi) {
    return f2bf(lo) | (f2bf(hi) << 16);
}
__device__ __forceinline__ float bflo(unsigned int v) { return __uint_as_float(v << 16); }
__device__ __forceinline__ float bfhi(unsigned int v) { return __uint_as_float(v & 0xffff0000u); }

// ---------- WTs: W[k][n] f32 -> bf16 in MFMA FRAGMENT order ----------
__global__ void wt_kernel(const float* __restrict__ W, short* __restrict__ WTs) {
    int o = blockIdx.x * 256 + threadIdx.x;   // 32768
    int j    = o & 7;
    int lane = (o >> 3) & 63;
    int nt   = (o >> 9) & 7;
    int kc   = o >> 12;
    int n = nt * 16 + (lane & 15);
    int k = kc * 32 + (lane >> 4) * 8 + j;
    WTs[o] = (short)f2bf(W[k * 128 + n]);
}

// ---------- GEMM via bf16 MFMA, REGISTER-DIRECT A (no LDS, no barrier) ----------
__global__ __launch_bounds__(256) void gemm_kernel(const float* __restrict__ feat,
                                                   const short* __restrict__ WTs,
                                                   const float* __restrict__ al_w,
                                                   const float* __restrict__ al_b,
                                                   const float* __restrict__ ar_w,
                                                   const float* __restrict__ ar_b,
                                                   unsigned int* __restrict__ seqb,
                                                   float* __restrict__ f1,
                                                   float* __restrict__ f2) {
    const int tid  = threadIdx.x;
    const int w    = tid >> 6;      // wave 0..3 -> rows tb + w*16 ..
    const int lane = tid & 63;
    const int m    = lane & 15;     // A row / B col within tile
    const int q    = lane >> 4;     // quad -> k offset q*8, C rows q*4..q*4+3
    const int tb   = blockIdx.x * 64;

    int gr = tb + w * 16 + m; if (gr >= N_NODES) gr = N_NODES - 1;   // clamp tail
    const float4* fp = (const float4*)(feat + (size_t)gr * 256) + q * 2;

    // ---- A-fragments: 8 x (two float4 loads + pack to bf16x8) = 32 VGPR ----
    bf8_t a[8];
#pragma unroll
    for (int kc = 0; kc < 8; kc++) {
        float4 v0 = fp[kc * 8];          // feat[gr][kc*32 + q*8 + 0..3]
        float4 v1 = fp[kc * 8 + 1];      // feat[gr][kc*32 + q*8 + 4..7]
        uint4 u = make_uint4(packbf(v0.x, v0.y), packbf(v0.z, v0.w),
                             packbf(v1.x, v1.y), packbf(v1.z, v1.w));
        a[kc] = *(const bf8_t*)&u;
    }

    const short* bb = WTs + (size_t)lane * 8;   // + (kc*8+nt)*512 shorts

    f4_t acc[8];
#pragma unroll
    for (int nt = 0; nt < 8; nt++) acc[nt] = (f4_t)(0.f);

#pragma unroll
    for (int kc = 0; kc < 8; kc++) {
#pragma unroll
        for (int nt = 0; nt < 8; nt++) {
            bf8_t b = *(const bf8_t*)(bb + (kc * 8 + nt) * 512);
            acc[nt] = __builtin_amdgcn_mfma_f32_16x16x32_bf16(a[kc], b, acc[nt], 0, 0, 0);
        }
    }

    // ---- epilogue 1: seqb packed bf16x2 (pair adjacent cols via shfl_xor(1)) ----
    const int node_base = tb + w * 16 + q * 4;
#pragma unroll
    for (int nt = 0; nt < 8; nt++) {
#pragma unroll
        for (int j = 0; j < 4; j++) {
            float own   = acc[nt][j];
            float other = __shfl_xor(own, 1);
            int node = node_base + j;
            if (!(lane & 1) && node < N_NODES)
                seqb[(size_t)node * 64 + nt * 8 + (m >> 1)] = packbf(own, other);
        }
    }

    // ---- epilogue 2: f1/f2 = seq . al_w / ar_w (reduce over cols = lanes m) ----
    float p1[4] = {0.f, 0.f, 0.f, 0.f}, p2[4] = {0.f, 0.f, 0.f, 0.f};
#pragma unroll
    for (int nt = 0; nt < 8; nt++) {
        float av = al_w[nt * 16 + m];
        float rv = ar_w[nt * 16 + m];
#pragma unroll
        for (int j = 0; j < 4; j++) {
            p1[j] += acc[nt][j] * av;
            p2[j] += acc[nt][j] * rv;
        }
    }
#pragma unroll
    for (int j = 0; j < 4; j++) {
#pragma unroll
        for (int mk = 1; mk < 16; mk <<= 1) {
            p1[j] += __shfl_xor(p1[j], mk);
            p2[j] += __shfl_xor(p2[j], mk);
        }
    }
    if (m == 0) {
        float alb = al_b[0], arb = ar_b[0];
#pragma unroll
        for (int j = 0; j < 4; j++) {
            int node = node_base + j;
            if (node < N_NODES) {
                f1[node] = p1[j] + alb;
                f2[node] = p2[j] + arb;
            }
        }
    }
}

// ---------- chunk-privatized histogram + within-chunk rank (NO global atomics) ----------
__global__ __launch_bounds__(1024) void hist_kernel(const int* __restrict__ row,
                                                    unsigned char* __restrict__ localrank,
                                                    unsigned int* __restrict__ histpk) {
    __shared__ unsigned int h[HWORDS];    // 100 KB
    const int tid = threadIdx.x;
    for (int i = tid; i < HWORDS; i += 1024) h[i] = 0u;
    __syncthreads();

    const int base = blockIdx.x * CHUNK;
#pragma unroll
    for (int it = 0; it < CHUNK / 1024; it++) {
        int e = base + it * 1024 + tid;
        int r = row[e];
        unsigned int sh  = (unsigned int)(r & 3) * 8u;
        unsigned int old = atomicAdd(&h[r >> 2], 1u << sh);
        localrank[e] = (unsigned char)((old >> sh) & 0xffu);
    }
    __syncthreads();

    unsigned int* dst = histpk + (size_t)blockIdx.x * HWORDS;
    for (int i = tid; i < HWORDS; i += 1024) dst[i] = h[i];
}

// ---------- cross-chunk prefix, phase A: 5 parallel groups of 25 chunks ----------
__global__ __launch_bounds__(256) void scanbA_kernel(const unsigned int* __restrict__ histpk,
                                                     unsigned int* __restrict__ blockpre,
                                                     unsigned int* __restrict__ gsum) {
    int id = blockIdx.x * 256 + threadIdx.x;
    if (id >= NGRP * HWORDS) return;
    int g = id / HWORDS;
    int w = id - g * HWORDS;
    const unsigned int* hp = histpk   + (size_t)(g * GLEN) * HWORDS + w;
    unsigned int*       bp = blockpre + (size_t)(g * GLEN) * HWORDS + w;
    unsigned int run = 0u;
#pragma unroll 5
    for (int i = 0; i < GLEN; i++) {
        unsigned int hv = hp[(size_t)i * HWORDS];
        bp[(size_t)i * HWORDS] = run;
        run += hv;
    }
    gsum[(size_t)g * HWORDS + w] = run;
}

// ---------- fused: group-sum scan (-> bases in gsum, cnt) + node-degree block scan ----
__global__ __launch_bounds__(256) void degscan_kernel(unsigned int* __restrict__ gsum,
                                                      uint4* __restrict__ cnt4,
                                                      unsigned int* __restrict__ offs,
                                                      unsigned int* __restrict__ bsums) {
    __shared__ unsigned int s[256];
    const int t = threadIdx.x;
    const int w = blockIdx.x * 256 + t;
    unsigned int run = 0u, T = 0u;
    unsigned int d0 = 0, d1 = 0, d2 = 0;
    if (w < HWORDS) {
#pragma unroll
        for (int g = 0; g < NGRP; g++) {
            unsigned int v = gsum[(size_t)g * HWORDS + w];
            gsum[(size_t)g * HWORDS + w] = run;     // exclusive group base (packed u8x4)
            run += v;                                // byte-wise; totals <= 255
        }
        cnt4[w] = make_uint4(run & 0xffu, (run >> 8) & 0xffu,
                             (run >> 16) & 0xffu, run >> 24);
        d0 = run & 0xffu; d1 = (run >> 8) & 0xffu; d2 = (run >> 16) & 0xffu;
        T = d0 + d1 + d2 + (run >> 24);
    }
    s[t] = T; __syncthreads();
    for (int d = 1; d < 256; d <<= 1) {
        unsigned int x = (t >= d) ? s[t - d] : 0u;
        __syncthreads();
        s[t] += x;
        __syncthreads();
    }
    if (w < HWORDS) {
        unsigned int excl = s[t] - T;
        offs[w * 4 + 0] = excl;
        offs[w * 4 + 1] = excl + d0;
        offs[w * 4 + 2] = excl + d0 + d1;
        offs[w * 4 + 3] = excl + d0 + d1 + d2;
    }
    if (t == 255) bsums[blockIdx.x] = s[255];
}

__global__ void scan2(const unsigned int* __restrict__ bsums,
                      unsigned int* __restrict__ bexcl, int nb) {
    __shared__ unsigned int s[512];
    int t = threadIdx.x;
    unsigned int v = (t < nb) ? bsums[t] : 0u;
    s[t] = v; __syncthreads();
    for (int d = 1; d < 512; d <<= 1) {
        unsigned int x = (t >= d) ? s[t - d] : 0u;
        __syncthreads();
        s[t] += x;
        __syncthreads();
    }
    if (t < nb) bexcl[t] = s[t] - v;
}

// ---------- fused: offs += block base; offs_g = offs + group base; cursor init ----
__global__ __launch_bounds__(256) void scan3g_kernel(unsigned int* __restrict__ offs,
                                                     const unsigned int* __restrict__ bexcl,
                                                     const unsigned int* __restrict__ gsum,
                                                     unsigned int* __restrict__ offs_g,
                                                     unsigned int* __restrict__ cursor) {
    if (blockIdx.x == 0 && threadIdx.x < NBUK)
        cursor[threadIdx.x * 16] = (unsigned int)threadIdx.x * BW;   // static bucket bases
    int i = blockIdx.x * 256 + threadIdx.x;
    if (i >= N_NODES) return;
    unsigned int o = offs[i] + bexcl[i >> 10];   // 1024 nodes per degscan block
    offs[i] = o;
    unsigned int sh = (unsigned int)(i & 3) * 8u;
#pragma unroll
    for (int g = 0; g < NGRP; g++) {
        unsigned int gb = (gsum[(size_t)g * HWORDS + (i >> 2)] >> sh) & 0xffu;
        offs_g[(size_t)g * N_NODES + i] = o + gb;
    }
}

// ---------- P1 bucket: 1250 blocks x 256 thr (grid-starved fix) ----------
// R10 lesson: 250 blocks = 2000 waves = 24% machine capacity cap -- the kernel
// was GRID-limited, not LDS/VGPR-limited. 2560-edge tiles give 5000 waves
// (~61% capacity) so TLP hides the L2-resident blockpre/offs_g gathers.
// p[10] register stash (static indices), 1 KB LDS hcnt, padded global cursors.
__global__ __launch_bounds__(256) void bucket_kernel(const int* __restrict__ row,
                                                     const int* __restrict__ col,
                                                     const unsigned char* __restrict__ localrank,
                                                     const unsigned int* __restrict__ blockpre,
                                                     const unsigned int* __restrict__ offs_g,
                                                     unsigned int* __restrict__ cursor,
                                                     unsigned int* __restrict__ records) {
    __shared__ unsigned int hcnt[NBUK];    // 1 KB: counts -> running cursors
    const int tid = threadIdx.x;
    const int blk = blockIdx.x;
    const int b   = blk / (CHUNK / P1TILE);   // chunk (10 blocks per chunk)
    const unsigned int* bp = blockpre + (size_t)b * HWORDS;
    const unsigned int* og = offs_g + (size_t)(b / GLEN) * N_NODES;
    hcnt[tid] = 0u;                        // 256 threads == NBUK
    __syncthreads();

    const int base = blk * P1TILE;
    unsigned int p[P1PT];                  // 10 VGPRs, static indices only
#pragma unroll
    for (int it = 0; it < P1PT; it++) {
        int e = base + it * 256 + tid;
        int r = row[e];
        unsigned int pb = (bp[r >> 2] >> ((unsigned int)(r & 3) * 8u)) & 0xffu;
        p[it] = og[r] + pb + (unsigned int)localrank[e];
        atomicAdd(&hcnt[p[it] / BW], 1u);
    }
    __syncthreads();
    {
        unsigned int c = hcnt[tid];
        hcnt[tid] = atomicAdd(&cursor[tid * 16], c);   // reserve [base, base+c)
    }
    __syncthreads();
#pragma unroll
    for (int it = 0; it < P1PT; it++) {
        int e = base + it * 256 + tid;
        unsigned int buk = p[it] / BW;
        unsigned int idx = atomicAdd(&hcnt[buk], 1u);
        records[idx] = ((p[it] - buk * BW) << 17) | (unsigned int)col[e];
    }
}

// ---------- P2: windowed scatter -- contiguous record read, LDS window, coalesced write --
__global__ __launch_bounds__(256) void scatter2_kernel(const unsigned int* __restrict__ records,
                                                       int* __restrict__ sorted_c) {
    __shared__ int win[BW];   // 50 KB
    const int tid = threadIdx.x;
    const unsigned int gb = (unsigned int)blockIdx.x * BW;
    const uint4* rec4 = (const uint4*)(records + gb);
    for (int i = tid; i < BW / 4; i += 256) {       // 3125 uint4
        uint4 r4 = rec4[i];
        win[r4.x >> 17] = (int)(r4.x & 0x1FFFFu);
        win[r4.y >> 17] = (int)(r4.y & 0x1FFFFu);
        win[r4.z >> 17] = (int)(r4.z & 0x1FFFFu);
        win[r4.w >> 17] = (int)(r4.w & 0x1FFFFu);
    }
    __syncthreads();
    int4* dst = (int4*)(sorted_c + gb);
    const int4* src = (const int4*)win;
    for (int i = tid; i < BW / 4; i += 256) dst[i] = src[i];
}

// ---------- row aggregate (split into two half-grids for profiler visibility) ----------
__device__ __forceinline__ void row_body(int wid_base,
                                         const uint4* __restrict__ seqb4,
                                         const int* __restrict__ sorted_c,
                                         const unsigned int* __restrict__ offs,
                                         const unsigned int* __restrict__ cnt,
                                         const float* __restrict__ f1,
                                         const float* __restrict__ f2,
                                         const float* __restrict__ bias,
                                         float* __restrict__ out) {
    int wid  = wid_base + ((blockIdx.x * 256 + threadIdx.x) >> 6);
    int lane = threadIdx.x & 63;
    int g    = lane >> 4;        // edge group 0..3
    int j4   = lane & 15;        // uint4 index within row: cols 8*j4 .. 8*j4+7
    unsigned int start = offs[wid];
    unsigned int deg   = cnt[wid];
    const int* sc = sorted_c + start;
    float f1r = f1[wid];

    float a0 = 0.f, a1 = 0.f, a2 = 0.f, a3 = 0.f;
    float a4 = 0.f, a5 = 0.f, a6 = 0.f, a7 = 0.f, ss = 0.f;

    unsigned int k = 0;
    for (; k + 16 <= deg; k += 16) {         // 16 edges: group g handles k+g+4i
        int c0 = sc[k + g];
        int c1 = sc[k + 4 + g];
        int c2 = sc[k + 8 + g];
        int c3 = sc[k + 12 + g];
        uint4 v0 = seqb4[(unsigned)c0 * 16u + j4];
        uint4 v1 = seqb4[(unsigned)c1 * 16u + j4];
        uint4 v2 = seqb4[(unsigned)c2 * 16u + j4];
        uint4 v3 = seqb4[(unsigned)c3 * 16u + j4];
        float t0 = f1r + f2[c0], t1 = f1r + f2[c1];
        float t2 = f1r + f2[c2], t3 = f1r + f2[c3];
        float w0 = __expf(fmaxf(t0, ALPHA * t0));
        float w1 = __expf(fmaxf(t1, ALPHA * t1));
        float w2 = __expf(fmaxf(t2, ALPHA * t2));
        float w3 = __expf(fmaxf(t3, ALPHA * t3));
        ss += (w0 + w1) + (w2 + w3);
        a0 += w0 * bflo(v0.x); a1 += w0 * bfhi(v0.x);
        a2 += w0 * bflo(v0.y); a3 += w0 * bfhi(v0.y);
        a4 += w0 * bflo(v0.z); a5 += w0 * bfhi(v0.z);
        a6 += w0 * bflo(v0.w); a7 += w0 * bfhi(v0.w);
        a0 += w1 * bflo(v1.x); a1 += w1 * bfhi(v1.x);
        a2 += w1 * bflo(v1.y); a3 += w1 * bfhi(v1.y);
        a4 += w1 * bflo(v1.z); a5 += w1 * bfhi(v1.z);
        a6 += w1 * bflo(v1.w); a7 += w1 * bfhi(v1.w);
        a0 += w2 * bflo(v2.x); a1 += w2 * bfhi(v2.x);
        a2 += w2 * bflo(v2.y); a3 += w2 * bfhi(v2.y);
        a4 += w2 * bflo(v2.z); a5 += w2 * bfhi(v2.z);
        a6 += w2 * bflo(v2.w); a7 += w2 * bfhi(v2.w);
        a0 += w3 * bflo(v3.x); a1 += w3 * bfhi(v3.x);
        a2 += w3 * bflo(v3.y); a3 += w3 * bfhi(v3.y);
        a4 += w3 * bflo(v3.z); a5 += w3 * bfhi(v3.z);
        a6 += w3 * bflo(v3.w); a7 += w3 * bfhi(v3.w);
    }
    for (; k + 8 <= deg; k += 8) {
        int ca = sc[k + g];
        int cb = sc[k + 4 + g];
        uint4 va = seqb4[(unsigned)ca * 16u + j4];
        uint4 vb = seqb4[(unsigned)cb * 16u + j4];
        float ta = f1r + f2[ca];
        float tb = f1r + f2[cb];
        float wa = __expf(fmaxf(ta, ALPHA * ta));
        float wb = __expf(fmaxf(tb, ALPHA * tb));
        ss += wa + wb;
        a0 += wa * bflo(va.x); a1 += wa * bfhi(va.x);
        a2 += wa * bflo(va.y); a3 += wa * bfhi(va.y);
        a4 += wa * bflo(va.z); a5 += wa * bfhi(va.z);
        a6 += wa * bflo(va.w); a7 += wa * bfhi(va.w);
        a0 += wb * bflo(vb.x); a1 += wb * bfhi(vb.x);
        a2 += wb * bflo(vb.y); a3 += wb * bfhi(vb.y);
        a4 += wb * bflo(vb.z); a5 += wb * bfhi(vb.z);
        a6 += wb * bflo(vb.w); a7 += wb * bfhi(vb.w);
    }
    for (; k < deg; k += 4) {
        unsigned int ke = k + g;
        int c = sc[ke < deg ? ke : deg - 1];
        uint4 v = seqb4[(unsigned)c * 16u + j4];
        float t = f1r + f2[c];
        float w = __expf(fmaxf(t, ALPHA * t));
        if (ke >= deg) w = 0.f;
        ss += w;
        a0 += w * bflo(v.x); a1 += w * bfhi(v.x);
        a2 += w * bflo(v.y); a3 += w * bfhi(v.y);
        a4 += w * bflo(v.z); a5 += w * bfhi(v.z);
        a6 += w * bflo(v.w); a7 += w * bfhi(v.w);
    }

    a0 += __shfl_xor(a0, 16); a0 += __shfl_xor(a0, 32);
    a1 += __shfl_xor(a1, 16); a1 += __shfl_xor(a1, 32);
    a2 += __shfl_xor(a2, 16); a2 += __shfl_xor(a2, 32);
    a3 += __shfl_xor(a3, 16); a3 += __shfl_xor(a3, 32);
    a4 += __shfl_xor(a4, 16); a4 += __shfl_xor(a4, 32);
    a5 += __shfl_xor(a5, 16); a5 += __shfl_xor(a5, 32);
    a6 += __shfl_xor(a6, 16); a6 += __shfl_xor(a6, 32);
    a7 += __shfl_xor(a7, 16); a7 += __shfl_xor(a7, 32);
    ss += __shfl_xor(ss, 16); ss += __shfl_xor(ss, 32);

    if (g == 0) {
        float inv = (deg > 0) ? 1.f / ss : 0.f;   // empty row -> bias only
        float4 b0 = ((const float4*)bias)[j4 * 2];
        float4 b1 = ((const float4*)bias)[j4 * 2 + 1];
        float4* orow = (float4*)(out + (size_t)wid * D_OUT);
        orow[j4 * 2]     = make_float4(a0 * inv + b0.x, a1 * inv + b0.y,
                                       a2 * inv + b0.z, a3 * inv + b0.w);
        orow[j4 * 2 + 1] = make_float4(a4 * inv + b1.x, a5 * inv + b1.y,
                                       a6 * inv + b1.z, a7 * inv + b1.w);
    }
}

__global__ __launch_bounds__(256) void rowA_kernel(const uint4* __restrict__ seqb4,
                                                   const int* __restrict__ sorted_c,
                                                   const unsigned int* __restrict__ offs,
                                                   const unsigned int* __restrict__ cnt,
                                                   const float* __restrict__ f1,
                                                   const float* __restrict__ f2,
                                                   const float* __restrict__ bias,
                                                   float* __restrict__ out) {
    row_body(0, seqb4, sorted_c, offs, cnt, f1, f2, bias, out);
}
__global__ __launch_bounds__(256) void rowB_kernel(const uint4* __restrict__ seqb4,
                                                   const int* __restrict__ sorted_c,
                                                   const unsigned int* __restrict__ offs,
                                                   const unsigned int* __restrict__ cnt,
                                                   const float* __restrict__ f1,
                                                   const float* __restrict__ f2,
                                                   const float* __restrict__ bias,
                                                   float* __restrict__ out) {
    row_body(N_NODES / 2, seqb4, sorted_c, offs, cnt, f1, f2, bias, out);
}

extern "C" void kernel_launch(void* const* d_in, const int* in_sizes, int n_in,
                              void* d_out, int out_size, void* d_ws, size_t ws_size,
                              hipStream_t stream) {
    const float* feat = (const float*)d_in[0];
    const int*   row  = (const int*)d_in[1];
    const int*   col  = (const int*)d_in[2];
    const float* W    = (const float*)d_in[3];
    const float* al_w = (const float*)d_in[4];
    const float* al_b = (const float*)d_in[5];
    const float* ar_w = (const float*)d_in[6];
    const float* ar_b = (const float*)d_in[7];
    const float* bias = (const float*)d_in[8];
    float* out = (float*)d_out;

    char* ws = (char*)d_ws;
    size_t off = 0;
    auto carve = [&](size_t bytes) -> void* {
        off = (off + 255) & ~(size_t)255;
        void* p = ws + off;
        off += bytes;
        return p;
    };
    unsigned int* seqb     = (unsigned int*)carve((size_t)N_NODES * 64 * 4);  // bf16x2 packed
    float*        f1       = (float*)       carve((size_t)N_NODES * 4);
    float*        f2       = (float*)       carve((size_t)N_NODES * 4);
    unsigned int* cnt      = (unsigned int*)carve((size_t)N_NODES * 4);
    unsigned int* offs     = (unsigned int*)carve((size_t)N_NODES * 4);
    unsigned int* bsums    = (unsigned int*)carve(1024 * 4);
    unsigned int* bexcl    = (unsigned int*)carve(1024 * 4);
    unsigned int* cursor   = (unsigned int*)carve(NBUK * 64);   // 1 cursor per 64 B line
    short*        WTs      = (short*)       carve((size_t)D_IN * D_OUT * 2);  // bf16 W frag-order
    unsigned char* localrank = (unsigned char*)carve((size_t)N_EDGES);
    unsigned int* gsum     = (unsigned int*)carve((size_t)NGRP * HWORDS * 4);     // 0.5 MB
    unsigned int* offs_g   = (unsigned int*)carve((size_t)NGRP * N_NODES * 4);    // 2 MB
    // Region A (12.8 MB): histpk (hist -> scanbA) then records (bucket -> scatter2).
    unsigned int* regionA  = (unsigned int*)carve((size_t)N_EDGES * 4);
    unsigned int* histpk   = regionA;
    unsigned int* records  = regionA;
    // Region B (12.8 MB): blockpre (scanbA -> bucket) then sorted_c (scatter2 -> row).
    unsigned int* regionB  = (unsigned int*)carve((size_t)N_EDGES * 4);
    unsigned int* blockpre = regionB;
    int*          sorted_c = (int*)regionB;
    (void)ws_size; (void)in_sizes; (void)n_in; (void)out_size;

    const int nb_nodes = (N_NODES + 255) / 256;       // 391
    const int nb_gemm  = (N_NODES + 63) / 64;         // 1563 (last block guarded)
    const int nb_gw    = (NGRP * HWORDS + 255) / 256; // 489
    const int nb_deg   = (HWORDS + 255) / 256;        // 98
    const int nb_p1    = N_EDGES / P1TILE;            // 1250
    const int nb_rowh  = (N_NODES / 2) / 4;           // 12500 (4 waves/block, exact)

    wt_kernel<<<(D_IN * D_OUT) / 256, 256, 0, stream>>>(W, WTs);
    gemm_kernel<<<nb_gemm, 256, 0, stream>>>(feat, WTs, al_w, al_b, ar_w, ar_b, seqb, f1, f2);
    hist_kernel<<<NB_HIST, 1024, 0, stream>>>(row, localrank, histpk);
    scanbA_kernel<<<nb_gw, 256, 0, stream>>>(histpk, blockpre, gsum);
    degscan_kernel<<<nb_deg, 256, 0, stream>>>(gsum, (uint4*)cnt, offs, bsums);
    scan2<<<1, 512, 0, stream>>>(bsums, bexcl, nb_deg);
    scan3g_kernel<<<nb_nodes, 256, 0, stream>>>(offs, bexcl, gsum, offs_g, cursor);
    bucket_kernel<<<nb_p1, 256, 0, stream>>>(row, col, localrank, blockpre, offs_g,
                                             cursor, records);
    scatter2_kernel<<<NBUK, 256, 0, stream>>>(records, sorted_c);
    rowA_kernel<<<nb_rowh, 256, 0, stream>>>((const uint4*)seqb, sorted_c, offs, cnt, f1, f2, bias, out);
    rowB_kernel<<<nb_rowh, 256, 0, stream>>>((const uint4*)seqb, sorted_c, offs, cnt, f1, f2, bias, out);
}

// Round 12
// 387.881 us; speedup vs baseline: 1.1919x; 1.1919x over previous
//
#include <hip/hip_runtime.h>
#include <math.h>

#define N_NODES 100000
#define N_EDGES 3200000
#define D_IN    256
#define D_OUT   128
#define ALPHA   0.2f

// two-level row-range bucket sort (order within a row is irrelevant: softmax+sum
// are commutative, so NO within-row ranks are needed -> no hist/scan pipeline).
#define RPB     128                    // rows per bucket (bucket = row >> 7)
#define NBUK2   782                    // ceil(100000/128)
#define MAXBUK  6144                   // LDS window cap: mean 4096 + 32 sigma
#define B2TILE  12800                  // edges per sizes/bucket2 block (250 blocks)
#define B2PT    (B2TILE / 512)         // 25 edges per thread

typedef short bf8_t  __attribute__((ext_vector_type(8)));   // 8 bf16 (MFMA A/B frag)
typedef float f4_t   __attribute__((ext_vector_type(4)));   // 4 f32  (MFMA C/D frag)

// round-to-nearest-even f32 -> bf16
__device__ __forceinline__ unsigned int f2bf(float x) {
    unsigned int u = __float_as_uint(x);
    return (u + 0x7fffu + ((u >> 16) & 1u)) >> 16;
}
__device__ __forceinline__ unsigned int packbf(float lo, float hi) {
    return f2bf(lo) | (f2bf(hi) << 16);
}
__device__ __forceinline__ float bflo(unsigned int v) { return __uint_as_float(v << 16); }
__device__ __forceinline__ float bfhi(unsigned int v) { return __uint_as_float(v & 0xffff0000u); }

// ---------- WTs: W[k][n] f32 -> bf16 in MFMA FRAGMENT order ----------
__global__ void wt_kernel(const float* __restrict__ W, short* __restrict__ WTs) {
    int o = blockIdx.x * 256 + threadIdx.x;   // 32768
    int j    = o & 7;
    int lane = (o >> 3) & 63;
    int nt   = (o >> 9) & 7;
    int kc   = o >> 12;
    int n = nt * 16 + (lane & 15);
    int k = kc * 32 + (lane >> 4) * 8 + j;
    WTs[o] = (short)f2bf(W[k * 128 + n]);
}

// ---------- GEMM via bf16 MFMA, REGISTER-DIRECT A (no LDS, no barrier) ----------
__global__ __launch_bounds__(256) void gemm_kernel(const float* __restrict__ feat,
                                                   const short* __restrict__ WTs,
                                                   const float* __restrict__ al_w,
                                                   const float* __restrict__ al_b,
                                                   const float* __restrict__ ar_w,
                                                   const float* __restrict__ ar_b,
                                                   unsigned int* __restrict__ seqb,
                                                   float* __restrict__ f1,
                                                   float* __restrict__ f2) {
    const int tid  = threadIdx.x;
    const int w    = tid >> 6;      // wave 0..3 -> rows tb + w*16 ..
    const int lane = tid & 63;
    const int m    = lane & 15;     // A row / B col within tile
    const int q    = lane >> 4;     // quad -> k offset q*8, C rows q*4..q*4+3
    const int tb   = blockIdx.x * 64;

    int gr = tb + w * 16 + m; if (gr >= N_NODES) gr = N_NODES - 1;   // clamp tail
    const float4* fp = (const float4*)(feat + (size_t)gr * 256) + q * 2;

    // ---- A-fragments: 8 x (two float4 loads + pack to bf16x8) = 32 VGPR ----
    bf8_t a[8];
#pragma unroll
    for (int kc = 0; kc < 8; kc++) {
        float4 v0 = fp[kc * 8];          // feat[gr][kc*32 + q*8 + 0..3]
        float4 v1 = fp[kc * 8 + 1];      // feat[gr][kc*32 + q*8 + 4..7]
        uint4 u = make_uint4(packbf(v0.x, v0.y), packbf(v0.z, v0.w),
                             packbf(v1.x, v1.y), packbf(v1.z, v1.w));
        a[kc] = *(const bf8_t*)&u;
    }

    const short* bb = WTs + (size_t)lane * 8;   // + (kc*8+nt)*512 shorts

    f4_t acc[8];
#pragma unroll
    for (int nt = 0; nt < 8; nt++) acc[nt] = (f4_t)(0.f);

#pragma unroll
    for (int kc = 0; kc < 8; kc++) {
#pragma unroll
        for (int nt = 0; nt < 8; nt++) {
            bf8_t b = *(const bf8_t*)(bb + (kc * 8 + nt) * 512);
            acc[nt] = __builtin_amdgcn_mfma_f32_16x16x32_bf16(a[kc], b, acc[nt], 0, 0, 0);
        }
    }

    // ---- epilogue 1: seqb packed bf16x2 (pair adjacent cols via shfl_xor(1)) ----
    const int node_base = tb + w * 16 + q * 4;
#pragma unroll
    for (int nt = 0; nt < 8; nt++) {
#pragma unroll
        for (int j = 0; j < 4; j++) {
            float own   = acc[nt][j];
            float other = __shfl_xor(own, 1);
            int node = node_base + j;
            if (!(lane & 1) && node < N_NODES)
                seqb[(size_t)node * 64 + nt * 8 + (m >> 1)] = packbf(own, other);
        }
    }

    // ---- epilogue 2: f1/f2 = seq . al_w / ar_w (reduce over cols = lanes m) ----
    float p1[4] = {0.f, 0.f, 0.f, 0.f}, p2[4] = {0.f, 0.f, 0.f, 0.f};
#pragma unroll
    for (int nt = 0; nt < 8; nt++) {
        float av = al_w[nt * 16 + m];
        float rv = ar_w[nt * 16 + m];
#pragma unroll
        for (int j = 0; j < 4; j++) {
            p1[j] += acc[nt][j] * av;
            p2[j] += acc[nt][j] * rv;
        }
    }
#pragma unroll
    for (int j = 0; j < 4; j++) {
#pragma unroll
        for (int mk = 1; mk < 16; mk <<= 1) {
            p1[j] += __shfl_xor(p1[j], mk);
            p2[j] += __shfl_xor(p2[j], mk);
        }
    }
    if (m == 0) {
        float alb = al_b[0], arb = ar_b[0];
#pragma unroll
        for (int j = 0; j < 4; j++) {
            int node = node_base + j;
            if (node < N_NODES) {
                f1[node] = p1[j] + alb;
                f2[node] = p2[j] + arb;
            }
        }
    }
}

// ---------- sizes: 782-bin histogram of row>>7 (bucket sizes) ----------
__global__ __launch_bounds__(512) void sizes_kernel(const int* __restrict__ row,
                                                    unsigned int* __restrict__ gsize) {
    __shared__ unsigned int h[NBUK2];   // 3.1 KB
    const int tid = threadIdx.x;
    for (int i = tid; i < NBUK2; i += 512) h[i] = 0u;
    __syncthreads();
    const int base = blockIdx.x * B2TILE;
#pragma unroll
    for (int it = 0; it < B2PT; it++) {
        unsigned int r = (unsigned int)row[base + it * 512 + tid];
        atomicAdd(&h[r >> 7], 1u);
    }
    __syncthreads();
    for (int i = tid; i < NBUK2; i += 512)
        if (h[i]) atomicAdd(&gsize[i], h[i]);
}

// ---------- scanS: exclusive scan of bucket sizes -> bases + cursor init ----------
__global__ __launch_bounds__(1024) void scanS_kernel(const unsigned int* __restrict__ gsize,
                                                     unsigned int* __restrict__ bukbase,
                                                     unsigned int* __restrict__ cursor) {
    __shared__ unsigned int s[1024];
    const int t = threadIdx.x;
    unsigned int v = (t < NBUK2) ? gsize[t] : 0u;
    s[t] = v; __syncthreads();
    for (int d = 1; d < 1024; d <<= 1) {
        unsigned int x = (t >= d) ? s[t - d] : 0u;
        __syncthreads();
        s[t] += x;
        __syncthreads();
    }
    if (t < NBUK2) {
        unsigned int excl = s[t] - v;
        bukbase[t] = excl;
        cursor[t * 16] = excl;                  // padded: 1 cursor per 64 B line
        if (t == NBUK2 - 1) bukbase[NBUK2] = s[t];   // = N_EDGES
    }
}

// ---------- bucket2: row-range bucket of (rlocal,col) -- NO metadata gathers ----------
// bucket = r>>7 (bit op), record = (r&127)<<17 | col (24 bits). Streaming reads,
// LDS counts, one padded global cursor atomic per touched bucket, dense ~66 B runs.
__global__ __launch_bounds__(512) void bucket2_kernel(const int* __restrict__ row,
                                                      const int* __restrict__ col,
                                                      unsigned int* __restrict__ cursor,
                                                      unsigned int* __restrict__ records) {
    __shared__ unsigned int hcnt[NBUK2];   // 3.1 KB: counts -> running cursors
    const int tid = threadIdx.x;
    const int base = blockIdx.x * B2TILE;
    for (int i = tid; i < NBUK2; i += 512) hcnt[i] = 0u;
    __syncthreads();

    unsigned int rec[B2PT], bk[B2PT];      // 50 VGPRs, static indices only
#pragma unroll
    for (int it = 0; it < B2PT; it++) {
        int e = base + it * 512 + tid;
        unsigned int r = (unsigned int)row[e];
        bk[it]  = r >> 7;
        rec[it] = ((r & 127u) << 17) | (unsigned int)col[e];
        atomicAdd(&hcnt[bk[it]], 1u);
    }
    __syncthreads();
    for (int i = tid; i < NBUK2; i += 512) {
        unsigned int c = hcnt[i];
        if (c) hcnt[i] = atomicAdd(&cursor[i * 16], c);   // reserve [base, base+c)
    }
    __syncthreads();
#pragma unroll
    for (int it = 0; it < B2PT; it++) {
        unsigned int idx = atomicAdd(&hcnt[bk[it]], 1u);
        records[idx] = rec[it];
    }
}

// ---------- csr: per-bucket group-by-row in LDS + coalesced write + offs/cnt ----------
// Block b: read its ~4096 records contiguously, 128-bin histogram + scan, scatter
// cols into LDS window grouped by row (any within-row order -- sum commutes),
// stream window to sorted_c, emit offs/cnt for its 128 rows. Replaces the entire
// hist/scanbA/degscan/scan2/scan3g/scatter2 pipeline.
__global__ __launch_bounds__(256) void csr_kernel(const unsigned int* __restrict__ records,
                                                  const unsigned int* __restrict__ bukbase,
                                                  int* __restrict__ sorted_c,
                                                  unsigned int* __restrict__ offs,
                                                  unsigned int* __restrict__ cnt) {
    __shared__ unsigned int h[RPB], sc[RPB], cur[RPB];
    __shared__ int win[MAXBUK];   // 24 KB
    const int tid = threadIdx.x;
    const int b   = blockIdx.x;
    const unsigned int base = bukbase[b];
    const int nrec = (int)(bukbase[b + 1] - base);

    if (tid < RPB) h[tid] = 0u;
    __syncthreads();
    for (int i = tid; i < nrec; i += 256)
        atomicAdd(&h[records[base + i] >> 17], 1u);
    __syncthreads();
    if (tid < RPB) sc[tid] = h[tid];
    __syncthreads();
    for (int d = 1; d < RPB; d <<= 1) {
        unsigned int x = (tid < RPB && tid >= d) ? sc[tid - d] : 0u;
        __syncthreads();
        if (tid < RPB) sc[tid] += x;
        __syncthreads();
    }
    if (tid < RPB) cur[tid] = sc[tid] - h[tid];   // exclusive local offset
    __syncthreads();
    for (int i = tid; i < nrec; i += 256) {
        unsigned int rec = records[base + i];
        unsigned int idx = atomicAdd(&cur[rec >> 17], 1u);
        win[idx] = (int)(rec & 0x1FFFFu);
    }
    __syncthreads();
    for (int i = tid; i < nrec; i += 256)
        sorted_c[base + i] = win[i];
    if (tid < RPB) {
        int r = b * RPB + tid;
        if (r < N_NODES) {
            offs[r] = base + (sc[tid] - h[tid]);
            cnt[r]  = h[tid];
        }
    }
}

// ---------- row aggregate (split into two half-grids for profiler visibility) ----------
__device__ __forceinline__ void row_body(int wid_base,
                                         const uint4* __restrict__ seqb4,
                                         const int* __restrict__ sorted_c,
                                         const unsigned int* __restrict__ offs,
                                         const unsigned int* __restrict__ cnt,
                                         const float* __restrict__ f1,
                                         const float* __restrict__ f2,
                                         const float* __restrict__ bias,
                                         float* __restrict__ out) {
    int wid  = wid_base + ((blockIdx.x * 256 + threadIdx.x) >> 6);
    int lane = threadIdx.x & 63;
    int g    = lane >> 4;        // edge group 0..3
    int j4   = lane & 15;        // uint4 index within row: cols 8*j4 .. 8*j4+7
    unsigned int start = offs[wid];
    unsigned int deg   = cnt[wid];
    const int* sc = sorted_c + start;
    float f1r = f1[wid];

    float a0 = 0.f, a1 = 0.f, a2 = 0.f, a3 = 0.f;
    float a4 = 0.f, a5 = 0.f, a6 = 0.f, a7 = 0.f, ss = 0.f;

    unsigned int k = 0;
    for (; k + 16 <= deg; k += 16) {         // 16 edges: group g handles k+g+4i
        int c0 = sc[k + g];
        int c1 = sc[k + 4 + g];
        int c2 = sc[k + 8 + g];
        int c3 = sc[k + 12 + g];
        uint4 v0 = seqb4[(unsigned)c0 * 16u + j4];
        uint4 v1 = seqb4[(unsigned)c1 * 16u + j4];
        uint4 v2 = seqb4[(unsigned)c2 * 16u + j4];
        uint4 v3 = seqb4[(unsigned)c3 * 16u + j4];
        float t0 = f1r + f2[c0], t1 = f1r + f2[c1];
        float t2 = f1r + f2[c2], t3 = f1r + f2[c3];
        float w0 = __expf(fmaxf(t0, ALPHA * t0));
        float w1 = __expf(fmaxf(t1, ALPHA * t1));
        float w2 = __expf(fmaxf(t2, ALPHA * t2));
        float w3 = __expf(fmaxf(t3, ALPHA * t3));
        ss += (w0 + w1) + (w2 + w3);
        a0 += w0 * bflo(v0.x); a1 += w0 * bfhi(v0.x);
        a2 += w0 * bflo(v0.y); a3 += w0 * bfhi(v0.y);
        a4 += w0 * bflo(v0.z); a5 += w0 * bfhi(v0.z);
        a6 += w0 * bflo(v0.w); a7 += w0 * bfhi(v0.w);
        a0 += w1 * bflo(v1.x); a1 += w1 * bfhi(v1.x);
        a2 += w1 * bflo(v1.y); a3 += w1 * bfhi(v1.y);
        a4 += w1 * bflo(v1.z); a5 += w1 * bfhi(v1.z);
        a6 += w1 * bflo(v1.w); a7 += w1 * bfhi(v1.w);
        a0 += w2 * bflo(v2.x); a1 += w2 * bfhi(v2.x);
        a2 += w2 * bflo(v2.y); a3 += w2 * bfhi(v2.y);
        a4 += w2 * bflo(v2.z); a5 += w2 * bfhi(v2.z);
        a6 += w2 * bflo(v2.w); a7 += w2 * bfhi(v2.w);
        a0 += w3 * bflo(v3.x); a1 += w3 * bfhi(v3.x);
        a2 += w3 * bflo(v3.y); a3 += w3 * bfhi(v3.y);
        a4 += w3 * bflo(v3.z); a5 += w3 * bfhi(v3.z);
        a6 += w3 * bflo(v3.w); a7 += w3 * bfhi(v3.w);
    }
    for (; k + 8 <= deg; k += 8) {
        int ca = sc[k + g];
        int cb = sc[k + 4 + g];
        uint4 va = seqb4[(unsigned)ca * 16u + j4];
        uint4 vb = seqb4[(unsigned)cb * 16u + j4];
        float ta = f1r + f2[ca];
        float tb = f1r + f2[cb];
        float wa = __expf(fmaxf(ta, ALPHA * ta));
        float wb = __expf(fmaxf(tb, ALPHA * tb));
        ss += wa + wb;
        a0 += wa * bflo(va.x); a1 += wa * bfhi(va.x);
        a2 += wa * bflo(va.y); a3 += wa * bfhi(va.y);
        a4 += wa * bflo(va.z); a5 += wa * bfhi(va.z);
        a6 += wa * bflo(va.w); a7 += wa * bfhi(va.w);
        a0 += wb * bflo(vb.x); a1 += wb * bfhi(vb.x);
        a2 += wb * bflo(vb.y); a3 += wb * bfhi(vb.y);
        a4 += wb * bflo(vb.z); a5 += wb * bfhi(vb.z);
        a6 += wb * bflo(vb.w); a7 += wb * bfhi(vb.w);
    }
    for (; k < deg; k += 4) {
        unsigned int ke = k + g;
        int c = sc[ke < deg ? ke : deg - 1];
        uint4 v = seqb4[(unsigned)c * 16u + j4];
        float t = f1r + f2[c];
        float w = __expf(fmaxf(t, ALPHA * t));
        if (ke >= deg) w = 0.f;
        ss += w;
        a0 += w * bflo(v.x); a1 += w * bfhi(v.x);
        a2 += w * bflo(v.y); a3 += w * bfhi(v.y);
        a4 += w * bflo(v.z); a5 += w * bfhi(v.z);
        a6 += w * bflo(v.w); a7 += w * bfhi(v.w);
    }

    a0 += __shfl_xor(a0, 16); a0 += __shfl_xor(a0, 32);
    a1 += __shfl_xor(a1, 16); a1 += __shfl_xor(a1, 32);
    a2 += __shfl_xor(a2, 16); a2 += __shfl_xor(a2, 32);
    a3 += __shfl_xor(a3, 16); a3 += __shfl_xor(a3, 32);
    a4 += __shfl_xor(a4, 16); a4 += __shfl_xor(a4, 32);
    a5 += __shfl_xor(a5, 16); a5 += __shfl_xor(a5, 32);
    a6 += __shfl_xor(a6, 16); a6 += __shfl_xor(a6, 32);
    a7 += __shfl_xor(a7, 16); a7 += __shfl_xor(a7, 32);
    ss += __shfl_xor(ss, 16); ss += __shfl_xor(ss, 32);

    if (g == 0) {
        float inv = (deg > 0) ? 1.f / ss : 0.f;   // empty row -> bias only
        float4 b0 = ((const float4*)bias)[j4 * 2];
        float4 b1 = ((const float4*)bias)[j4 * 2 + 1];
        float4* orow = (float4*)(out + (size_t)wid * D_OUT);
        orow[j4 * 2]     = make_float4(a0 * inv + b0.x, a1 * inv + b0.y,
                                       a2 * inv + b0.z, a3 * inv + b0.w);
        orow[j4 * 2 + 1] = make_float4(a4 * inv + b1.x, a5 * inv + b1.y,
                                       a6 * inv + b1.z, a7 * inv + b1.w);
    }
}

__global__ __launch_bounds__(256) void rowA_kernel(const uint4* __restrict__ seqb4,
                                                   const int* __restrict__ sorted_c,
                                                   const unsigned int* __restrict__ offs,
                                                   const unsigned int* __restrict__ cnt,
                                                   const float* __restrict__ f1,
                                                   const float* __restrict__ f2,
                                                   const float* __restrict__ bias,
                                                   float* __restrict__ out) {
    row_body(0, seqb4, sorted_c, offs, cnt, f1, f2, bias, out);
}
__global__ __launch_bounds__(256) void rowB_kernel(const uint4* __restrict__ seqb4,
                                                   const int* __restrict__ sorted_c,
                                                   const unsigned int* __restrict__ offs,
                                                   const unsigned int* __restrict__ cnt,
                                                   const float* __restrict__ f1,
                                                   const float* __restrict__ f2,
                                                   const float* __restrict__ bias,
                                                   float* __restrict__ out) {
    row_body(N_NODES / 2, seqb4, sorted_c, offs, cnt, f1, f2, bias, out);
}

extern "C" void kernel_launch(void* const* d_in, const int* in_sizes, int n_in,
                              void* d_out, int out_size, void* d_ws, size_t ws_size,
                              hipStream_t stream) {
    const float* feat = (const float*)d_in[0];
    const int*   row  = (const int*)d_in[1];
    const int*   col  = (const int*)d_in[2];
    const float* W    = (const float*)d_in[3];
    const float* al_w = (const float*)d_in[4];
    const float* al_b = (const float*)d_in[5];
    const float* ar_w = (const float*)d_in[6];
    const float* ar_b = (const float*)d_in[7];
    const float* bias = (const float*)d_in[8];
    float* out = (float*)d_out;

    char* ws = (char*)d_ws;
    size_t off = 0;
    auto carve = [&](size_t bytes) -> void* {
        off = (off + 255) & ~(size_t)255;
        void* p = ws + off;
        off += bytes;
        return p;
    };
    unsigned int* seqb     = (unsigned int*)carve((size_t)N_NODES * 64 * 4);  // 25.6 MB
    float*        f1       = (float*)       carve((size_t)N_NODES * 4);
    float*        f2       = (float*)       carve((size_t)N_NODES * 4);
    unsigned int* cnt      = (unsigned int*)carve((size_t)N_NODES * 4);
    unsigned int* offs     = (unsigned int*)carve((size_t)N_NODES * 4);
    short*        WTs      = (short*)       carve((size_t)D_IN * D_OUT * 2);
    unsigned int* gsize    = (unsigned int*)carve((size_t)NBUK2 * 4);
    unsigned int* bukbase  = (unsigned int*)carve((size_t)(NBUK2 + 1) * 4);
    unsigned int* cursor   = (unsigned int*)carve((size_t)NBUK2 * 64);   // padded lines
    unsigned int* records  = (unsigned int*)carve((size_t)N_EDGES * 4);  // 12.8 MB
    int*          sorted_c = (int*)         carve((size_t)N_EDGES * 4);  // 12.8 MB
    (void)ws_size; (void)in_sizes; (void)n_in; (void)out_size;

    const int nb_gemm = (N_NODES + 63) / 64;    // 1563 (last block guarded)
    const int nb_b2   = N_EDGES / B2TILE;       // 250 exact
    const int nb_rowh = (N_NODES / 2) / 4;      // 12500 (4 waves/block, exact)

    hipMemsetAsync(gsize, 0, (size_t)NBUK2 * 4, stream);
    wt_kernel<<<(D_IN * D_OUT) / 256, 256, 0, stream>>>(W, WTs);
    gemm_kernel<<<nb_gemm, 256, 0, stream>>>(feat, WTs, al_w, al_b, ar_w, ar_b, seqb, f1, f2);
    sizes_kernel<<<nb_b2, 512, 0, stream>>>(row, gsize);
    scanS_kernel<<<1, 1024, 0, stream>>>(gsize, bukbase, cursor);
    bucket2_kernel<<<nb_b2, 512, 0, stream>>>(row, col, cursor, records);
    csr_kernel<<<NBUK2, 256, 0, stream>>>(records, bukbase, sorted_c, offs, cnt);
    rowA_kernel<<<nb_rowh, 256, 0, stream>>>((const uint4*)seqb, sorted_c, offs, cnt, f1, f2, bias, out);
    rowB_kernel<<<nb_rowh, 256, 0, stream>>>((const uint4*)seqb, sorted_c, offs, cnt, f1, f2, bias, out);
}

// Round 13
// 362.636 us; speedup vs baseline: 1.2749x; 1.0696x over previous
//
#include <hip/hip_runtime.h>
#include <math.h>

#define N_NODES 100000
#define N_EDGES 3200000
#define D_IN    256
#define D_OUT   128
#define ALPHA   0.2f

// rank-free row-range bucket sort with FIXED bucket strides (no sizes/scan pass:
// softmax+sum commute, so edges only need GROUPING by row, and buckets can be
// padded -- offs[] absorbs the padding).
#define RPB     128                    // rows per bucket (bucket = row >> 7)
#define NBUK2   782                    // ceil(100000/128)
#define MAXBUK  6144                   // fixed stride: mean 4096 + 32 sigma
#define B2TILE  12800                  // edges per bucket2 block (250 blocks)
#define B2PT    (B2TILE / 512)         // 25 edges per thread (register stash)

typedef short bf8_t  __attribute__((ext_vector_type(8)));   // 8 bf16 (MFMA A/B frag)
typedef float f4_t   __attribute__((ext_vector_type(4)));   // 4 f32  (MFMA C/D frag)

// round-to-nearest-even f32 -> bf16
__device__ __forceinline__ unsigned int f2bf(float x) {
    unsigned int u = __float_as_uint(x);
    return (u + 0x7fffu + ((u >> 16) & 1u)) >> 16;
}
__device__ __forceinline__ unsigned int packbf(float lo, float hi) {
    return f2bf(lo) | (f2bf(hi) << 16);
}
__device__ __forceinline__ float bflo(unsigned int v) { return __uint_as_float(v << 16); }
__device__ __forceinline__ float bfhi(unsigned int v) { return __uint_as_float(v & 0xffff0000u); }

// ---------- WTs: W -> bf16 fragment order; also init bucket cursors ----------
__global__ void wt_kernel(const float* __restrict__ W, short* __restrict__ WTs,
                          unsigned int* __restrict__ cursor) {
    int o = blockIdx.x * 256 + threadIdx.x;   // 32768
    if (o < NBUK2) cursor[o * 16] = (unsigned int)o * MAXBUK;   // padded lines
    int j    = o & 7;
    int lane = (o >> 3) & 63;
    int nt   = (o >> 9) & 7;
    int kc   = o >> 12;
    int n = nt * 16 + (lane & 15);
    int k = kc * 32 + (lane >> 4) * 8 + j;
    WTs[o] = (short)f2bf(W[k * 128 + n]);
}

// ---------- GEMM via bf16 MFMA, REGISTER-DIRECT A (no LDS, no barrier) ----------
__global__ __launch_bounds__(256) void gemm_kernel(const float* __restrict__ feat,
                                                   const short* __restrict__ WTs,
                                                   const float* __restrict__ al_w,
                                                   const float* __restrict__ al_b,
                                                   const float* __restrict__ ar_w,
                                                   const float* __restrict__ ar_b,
                                                   unsigned int* __restrict__ seqb,
                                                   float* __restrict__ f1,
                                                   float* __restrict__ f2) {
    const int tid  = threadIdx.x;
    const int w    = tid >> 6;      // wave 0..3 -> rows tb + w*16 ..
    const int lane = tid & 63;
    const int m    = lane & 15;     // A row / B col within tile
    const int q    = lane >> 4;     // quad -> k offset q*8, C rows q*4..q*4+3
    const int tb   = blockIdx.x * 64;

    int gr = tb + w * 16 + m; if (gr >= N_NODES) gr = N_NODES - 1;   // clamp tail
    const float4* fp = (const float4*)(feat + (size_t)gr * 256) + q * 2;

    // ---- A-fragments: 8 x (two float4 loads + pack to bf16x8) = 32 VGPR ----
    bf8_t a[8];
#pragma unroll
    for (int kc = 0; kc < 8; kc++) {
        float4 v0 = fp[kc * 8];          // feat[gr][kc*32 + q*8 + 0..3]
        float4 v1 = fp[kc * 8 + 1];      // feat[gr][kc*32 + q*8 + 4..7]
        uint4 u = make_uint4(packbf(v0.x, v0.y), packbf(v0.z, v0.w),
                             packbf(v1.x, v1.y), packbf(v1.z, v1.w));
        a[kc] = *(const bf8_t*)&u;
    }

    const short* bb = WTs + (size_t)lane * 8;   // + (kc*8+nt)*512 shorts

    f4_t acc[8];
#pragma unroll
    for (int nt = 0; nt < 8; nt++) acc[nt] = (f4_t)(0.f);

#pragma unroll
    for (int kc = 0; kc < 8; kc++) {
#pragma unroll
        for (int nt = 0; nt < 8; nt++) {
            bf8_t b = *(const bf8_t*)(bb + (kc * 8 + nt) * 512);
            acc[nt] = __builtin_amdgcn_mfma_f32_16x16x32_bf16(a[kc], b, acc[nt], 0, 0, 0);
        }
    }

    // ---- epilogue 1: seqb packed bf16x2 (pair adjacent cols via shfl_xor(1)) ----
    const int node_base = tb + w * 16 + q * 4;
#pragma unroll
    for (int nt = 0; nt < 8; nt++) {
#pragma unroll
        for (int j = 0; j < 4; j++) {
            float own   = acc[nt][j];
            float other = __shfl_xor(own, 1);
            int node = node_base + j;
            if (!(lane & 1) && node < N_NODES)
                seqb[(size_t)node * 64 + nt * 8 + (m >> 1)] = packbf(own, other);
        }
    }

    // ---- epilogue 2: f1/f2 = seq . al_w / ar_w (reduce over cols = lanes m) ----
    float p1[4] = {0.f, 0.f, 0.f, 0.f}, p2[4] = {0.f, 0.f, 0.f, 0.f};
#pragma unroll
    for (int nt = 0; nt < 8; nt++) {
        float av = al_w[nt * 16 + m];
        float rv = ar_w[nt * 16 + m];
#pragma unroll
        for (int j = 0; j < 4; j++) {
            p1[j] += acc[nt][j] * av;
            p2[j] += acc[nt][j] * rv;
        }
    }
#pragma unroll
    for (int j = 0; j < 4; j++) {
#pragma unroll
        for (int mk = 1; mk < 16; mk <<= 1) {
            p1[j] += __shfl_xor(p1[j], mk);
            p2[j] += __shfl_xor(p2[j], mk);
        }
    }
    if (m == 0) {
        float alb = al_b[0], arb = ar_b[0];
#pragma unroll
        for (int j = 0; j < 4; j++) {
            int node = node_base + j;
            if (node < N_NODES) {
                f1[node] = p1[j] + alb;
                f2[node] = p2[j] + arb;
            }
        }
    }
}

// ---------- bucket2: row-range bucket of (rlocal,col), FIXED bases ----------
// bucket = r>>7 (bit op), record = (r&127)<<17 | col. Streaming reads, 25-deep
// ILP (no dependent gathers -> 250 blocks suffice), LDS counts, one padded
// global cursor atomic per touched bucket, ~66 B dense record runs.
__global__ __launch_bounds__(512) void bucket2_kernel(const int* __restrict__ row,
                                                      const int* __restrict__ col,
                                                      unsigned int* __restrict__ cursor,
                                                      unsigned int* __restrict__ records) {
    __shared__ unsigned int hcnt[NBUK2];   // 3.1 KB: counts -> running cursors
    const int tid = threadIdx.x;
    const int base = blockIdx.x * B2TILE;
    for (int i = tid; i < NBUK2; i += 512) hcnt[i] = 0u;
    __syncthreads();

    unsigned int rec[B2PT], bk[B2PT];      // 50 VGPRs, static indices only
#pragma unroll
    for (int it = 0; it < B2PT; it++) {
        int e = base + it * 512 + tid;
        unsigned int r = (unsigned int)row[e];
        bk[it]  = r >> 7;
        rec[it] = ((r & 127u) << 17) | (unsigned int)col[e];
        atomicAdd(&hcnt[bk[it]], 1u);
    }
    __syncthreads();
    for (int i = tid; i < NBUK2; i += 512) {
        unsigned int c = hcnt[i];
        if (c) hcnt[i] = atomicAdd(&cursor[i * 16], c);   // reserve [pos, pos+c)
    }
    __syncthreads();
#pragma unroll
    for (int it = 0; it < B2PT; it++) {
        unsigned int idx = atomicAdd(&hcnt[bk[it]], 1u);
        records[idx] = rec[it];
    }
}

// ---------- csr: per-bucket group-by-row in LDS + coalesced write + offs/cnt ----------
// Block b: nrec = cursor[b] - b*MAXBUK. Read records contiguously, 128-bin
// histogram + scan, scatter cols into LDS window grouped by row (any within-row
// order), stream window to sorted_c (padded layout -- offs absorbs the stride).
__global__ __launch_bounds__(256) void csr_kernel(const unsigned int* __restrict__ records,
                                                  const unsigned int* __restrict__ cursor,
                                                  int* __restrict__ sorted_c,
                                                  unsigned int* __restrict__ offs,
                                                  unsigned int* __restrict__ cnt) {
    __shared__ unsigned int h[RPB], sc[RPB], cur[RPB];
    __shared__ int win[MAXBUK];   // 24 KB
    const int tid = threadIdx.x;
    const int b   = blockIdx.x;
    const unsigned int base = (unsigned int)b * MAXBUK;
    const int nrec = (int)(cursor[b * 16] - base);

    if (tid < RPB) h[tid] = 0u;
    __syncthreads();
    for (int i = tid; i < nrec; i += 256)
        atomicAdd(&h[records[base + i] >> 17], 1u);
    __syncthreads();
    if (tid < RPB) sc[tid] = h[tid];
    __syncthreads();
    for (int d = 1; d < RPB; d <<= 1) {
        unsigned int x = (tid < RPB && tid >= d) ? sc[tid - d] : 0u;
        __syncthreads();
        if (tid < RPB) sc[tid] += x;
        __syncthreads();
    }
    if (tid < RPB) cur[tid] = sc[tid] - h[tid];   // exclusive local offset
    __syncthreads();
    for (int i = tid; i < nrec; i += 256) {
        unsigned int rec = records[base + i];
        unsigned int idx = atomicAdd(&cur[rec >> 17], 1u);
        win[idx] = (int)(rec & 0x1FFFFu);
    }
    __syncthreads();
    for (int i = tid; i < nrec; i += 256)
        sorted_c[base + i] = win[i];
    if (tid < RPB) {
        int r = b * RPB + tid;
        if (r < N_NODES) {
            offs[r] = base + (sc[tid] - h[tid]);
            cnt[r]  = h[tid];
        }
    }
}

// ---------- row aggregate (single kernel, one wave per row) ----------
__global__ __launch_bounds__(256) void row_kernel(const uint4* __restrict__ seqb4,
                                                  const int* __restrict__ sorted_c,
                                                  const unsigned int* __restrict__ offs,
                                                  const unsigned int* __restrict__ cnt,
                                                  const float* __restrict__ f1,
                                                  const float* __restrict__ f2,
                                                  const float* __restrict__ bias,
                                                  float* __restrict__ out) {
    int wid  = (blockIdx.x * 256 + threadIdx.x) >> 6;
    int lane = threadIdx.x & 63;
    int g    = lane >> 4;        // edge group 0..3
    int j4   = lane & 15;        // uint4 index within row: cols 8*j4 .. 8*j4+7
    if (wid >= N_NODES) return;
    unsigned int start = offs[wid];
    unsigned int deg   = cnt[wid];
    const int* sc = sorted_c + start;
    float f1r = f1[wid];

    float a0 = 0.f, a1 = 0.f, a2 = 0.f, a3 = 0.f;
    float a4 = 0.f, a5 = 0.f, a6 = 0.f, a7 = 0.f, ss = 0.f;

    unsigned int k = 0;
    for (; k + 16 <= deg; k += 16) {         // 16 edges: group g handles k+g+4i
        int c0 = sc[k + g];
        int c1 = sc[k + 4 + g];
        int c2 = sc[k + 8 + g];
        int c3 = sc[k + 12 + g];
        uint4 v0 = seqb4[(unsigned)c0 * 16u + j4];
        uint4 v1 = seqb4[(unsigned)c1 * 16u + j4];
        uint4 v2 = seqb4[(unsigned)c2 * 16u + j4];
        uint4 v3 = seqb4[(unsigned)c3 * 16u + j4];
        float t0 = f1r + f2[c0], t1 = f1r + f2[c1];
        float t2 = f1r + f2[c2], t3 = f1r + f2[c3];
        float w0 = __expf(fmaxf(t0, ALPHA * t0));
        float w1 = __expf(fmaxf(t1, ALPHA * t1));
        float w2 = __expf(fmaxf(t2, ALPHA * t2));
        float w3 = __expf(fmaxf(t3, ALPHA * t3));
        ss += (w0 + w1) + (w2 + w3);
        a0 += w0 * bflo(v0.x); a1 += w0 * bfhi(v0.x);
        a2 += w0 * bflo(v0.y); a3 += w0 * bfhi(v0.y);
        a4 += w0 * bflo(v0.z); a5 += w0 * bfhi(v0.z);
        a6 += w0 * bflo(v0.w); a7 += w0 * bfhi(v0.w);
        a0 += w1 * bflo(v1.x); a1 += w1 * bfhi(v1.x);
        a2 += w1 * bflo(v1.y); a3 += w1 * bfhi(v1.y);
        a4 += w1 * bflo(v1.z); a5 += w1 * bfhi(v1.z);
        a6 += w1 * bflo(v1.w); a7 += w1 * bfhi(v1.w);
        a0 += w2 * bflo(v2.x); a1 += w2 * bfhi(v2.x);
        a2 += w2 * bflo(v2.y); a3 += w2 * bfhi(v2.y);
        a4 += w2 * bflo(v2.z); a5 += w2 * bfhi(v2.z);
        a6 += w2 * bflo(v2.w); a7 += w2 * bfhi(v2.w);
        a0 += w3 * bflo(v3.x); a1 += w3 * bfhi(v3.x);
        a2 += w3 * bflo(v3.y); a3 += w3 * bfhi(v3.y);
        a4 += w3 * bflo(v3.z); a5 += w3 * bfhi(v3.z);
        a6 += w3 * bflo(v3.w); a7 += w3 * bfhi(v3.w);
    }
    for (; k + 8 <= deg; k += 8) {
        int ca = sc[k + g];
        int cb = sc[k + 4 + g];
        uint4 va = seqb4[(unsigned)ca * 16u + j4];
        uint4 vb = seqb4[(unsigned)cb * 16u + j4];
        float ta = f1r + f2[ca];
        float tb = f1r + f2[cb];
        float wa = __expf(fmaxf(ta, ALPHA * ta));
        float wb = __expf(fmaxf(tb, ALPHA * tb));
        ss += wa + wb;
        a0 += wa * bflo(va.x); a1 += wa * bfhi(va.x);
        a2 += wa * bflo(va.y); a3 += wa * bfhi(va.y);
        a4 += wa * bflo(va.z); a5 += wa * bfhi(va.z);
        a6 += wa * bflo(va.w); a7 += wa * bfhi(va.w);
        a0 += wb * bflo(vb.x); a1 += wb * bfhi(vb.x);
        a2 += wb * bflo(vb.y); a3 += wb * bfhi(vb.y);
        a4 += wb * bflo(vb.z); a5 += wb * bfhi(vb.z);
        a6 += wb * bflo(vb.w); a7 += wb * bfhi(vb.w);
    }
    for (; k < deg; k += 4) {
        unsigned int ke = k + g;
        int c = sc[ke < deg ? ke : deg - 1];
        uint4 v = seqb4[(unsigned)c * 16u + j4];
        float t = f1r + f2[c];
        float w = __expf(fmaxf(t, ALPHA * t));
        if (ke >= deg) w = 0.f;
        ss += w;
        a0 += w * bflo(v.x); a1 += w * bfhi(v.x);
        a2 += w * bflo(v.y); a3 += w * bfhi(v.y);
        a4 += w * bflo(v.z); a5 += w * bfhi(v.z);
        a6 += w * bflo(v.w); a7 += w * bfhi(v.w);
    }

    a0 += __shfl_xor(a0, 16); a0 += __shfl_xor(a0, 32);
    a1 += __shfl_xor(a1, 16); a1 += __shfl_xor(a1, 32);
    a2 += __shfl_xor(a2, 16); a2 += __shfl_xor(a2, 32);
    a3 += __shfl_xor(a3, 16); a3 += __shfl_xor(a3, 32);
    a4 += __shfl_xor(a4, 16); a4 += __shfl_xor(a4, 32);
    a5 += __shfl_xor(a5, 16); a5 += __shfl_xor(a5, 32);
    a6 += __shfl_xor(a6, 16); a6 += __shfl_xor(a6, 32);
    a7 += __shfl_xor(a7, 16); a7 += __shfl_xor(a7, 32);
    ss += __shfl_xor(ss, 16); ss += __shfl_xor(ss, 32);

    if (g == 0) {
        float inv = (deg > 0) ? 1.f / ss : 0.f;   // empty row -> bias only
        float4 b0 = ((const float4*)bias)[j4 * 2];
        float4 b1 = ((const float4*)bias)[j4 * 2 + 1];
        float4* orow = (float4*)(out + (size_t)wid * D_OUT);
        orow[j4 * 2]     = make_float4(a0 * inv + b0.x, a1 * inv + b0.y,
                                       a2 * inv + b0.z, a3 * inv + b0.w);
        orow[j4 * 2 + 1] = make_float4(a4 * inv + b1.x, a5 * inv + b1.y,
                                       a6 * inv + b1.z, a7 * inv + b1.w);
    }
}

extern "C" void kernel_launch(void* const* d_in, const int* in_sizes, int n_in,
                              void* d_out, int out_size, void* d_ws, size_t ws_size,
                              hipStream_t stream) {
    const float* feat = (const float*)d_in[0];
    const int*   row  = (const int*)d_in[1];
    const int*   col  = (const int*)d_in[2];
    const float* W    = (const float*)d_in[3];
    const float* al_w = (const float*)d_in[4];
    const float* al_b = (const float*)d_in[5];
    const float* ar_w = (const float*)d_in[6];
    const float* ar_b = (const float*)d_in[7];
    const float* bias = (const float*)d_in[8];
    float* out = (float*)d_out;

    char* ws = (char*)d_ws;
    size_t off = 0;
    auto carve = [&](size_t bytes) -> void* {
        off = (off + 255) & ~(size_t)255;
        void* p = ws + off;
        off += bytes;
        return p;
    };
    unsigned int* seqb     = (unsigned int*)carve((size_t)N_NODES * 64 * 4);  // 25.6 MB
    float*        f1       = (float*)       carve((size_t)N_NODES * 4);
    float*        f2       = (float*)       carve((size_t)N_NODES * 4);
    unsigned int* cnt      = (unsigned int*)carve((size_t)N_NODES * 4);
    unsigned int* offs     = (unsigned int*)carve((size_t)N_NODES * 4);
    short*        WTs      = (short*)       carve((size_t)D_IN * D_OUT * 2);
    unsigned int* cursor   = (unsigned int*)carve((size_t)NBUK2 * 64);        // padded lines
    unsigned int* records  = (unsigned int*)carve((size_t)NBUK2 * MAXBUK * 4); // 19.2 MB
    int*          sorted_c = (int*)         carve((size_t)NBUK2 * MAXBUK * 4); // 19.2 MB
    (void)ws_size; (void)in_sizes; (void)n_in; (void)out_size;

    const int nb_gemm = (N_NODES + 63) / 64;    // 1563 (last block guarded)
    const int nb_b2   = N_EDGES / B2TILE;       // 250 exact
    const int nb_row  = N_NODES / 4;            // 25000 exact (4 waves/block)

    wt_kernel<<<(D_IN * D_OUT) / 256, 256, 0, stream>>>(W, WTs, cursor);
    gemm_kernel<<<nb_gemm, 256, 0, stream>>>(feat, WTs, al_w, al_b, ar_w, ar_b, seqb, f1, f2);
    bucket2_kernel<<<nb_b2, 512, 0, stream>>>(row, col, cursor, records);
    csr_kernel<<<NBUK2, 256, 0, stream>>>(records, cursor, sorted_c, offs, cnt);
    row_kernel<<<nb_row, 256, 0, stream>>>((const uint4*)seqb, sorted_c, offs, cnt, f1, f2, bias, out);
}